// Round 24
// baseline (668.796 us; speedup 1.0000x reference)
//
#include <hip/hip_runtime.h>
#include <math.h>
#include <stdint.h>

constexpr int T_STEPS = 32;
constexpr int BATCH   = 128;
constexpr int IN_SZ   = 2048;   // K
constexpr int OUT_SZ  = 2048;   // N

// -------------------------------------------------------------------------
// FROZEN reference arithmetic (verified r14, absmax 0.0 r15-r23):
//   GEMM: f32, KC=512 uniform K-blocks; per element a fresh ascending-k
//         fmaf chain per block, f32 sequential block-combine.
//   Scan: f64 state, un = D*u + y (sep mul/add), s = (un>=1), u = un-s,
//         D = 1/(1+exp(-2)) in f64.
// r24 = r19's one-barrier dbuf pipeline at r23's 128-thread/low-VGPR point:
//   64x64 tile, 8x4 micro (r23 took 72 VGPR at 128 thr), B staged via
//   zero-VGPR global_load_lds DMA (2 issues/thread), A reg-prefetched
//   (8 VGPR), double-buffered LDS (2x8KB, y-buffer aliased -> 16 KB),
//   ONE barrier per K-step. 8 blocks/CU resident, 4 waves/SIMD.
// Per-element chain arithmetic bit-identical to r15-r23.
// -------------------------------------------------------------------------

__device__ __forceinline__ void async_lds16(const float* gsrc, float* lds_dst) {
    __builtin_amdgcn_global_load_lds(
        (const __attribute__((address_space(1))) uint32_t*)(uintptr_t)gsrc,
        (__attribute__((address_space(3))) uint32_t*)(uint32_t)(uintptr_t)lds_dst,
        16, 0, 0);
}

__global__ __launch_bounds__(128, 1) void Approx_OTPE_67181878444197_kernel(
        const float* __restrict__ x,
        const float* __restrict__ W,
        float* __restrict__ out) {
    constexpr int BK = 16, BM = 64, BN = 64;
    constexpr int ASZ = BK * BM;            // 1024 floats
    constexpr int BSZ = BK * BN;            // 1024 floats
    constexpr int BUF = ASZ + BSZ;          // 2048 floats per stage buffer
    constexpr int YSTR = BN + 1;            // 65
    constexpr int NIT = IN_SZ / BK;         // 128

    __shared__ float smem[2 * BUF];         // 16 KB; y (2080 f) aliases it

    const int o0  = blockIdx.x * BN;
    const int b0  = blockIdx.y * 2;
    const int tid = threadIdx.x;            // 0..127
    const int ty  = tid >> 4;               // 0..7  -> 8-row group
    const int tx  = tid & 15;               // 0..15 -> 4-col group
    const int wv  = tid >> 6;               // wave id 0..1 (wave-uniform)

    // A staging: m_local = tid>>1 (0..63), k-half = (tid&1)*8; m = 2t+b
    const int am = tid >> 1;
    const int ak = (tid & 1) * 8;
    const int at = am >> 1;
    const int ab = am & 1;
    const size_t aBase = ((size_t)at * BATCH + (size_t)(b0 + ab)) * IN_SZ + ak;

    // B staging (DMA, lane-linear k-major [k][64]): row br, col bc
    const int br = tid >> 4;                // 0..7 (first 8 rows; +8 second)
    const int bc = (tid & 15) * 4;          // 0..60

    float acc[8][4] = {};   // current KC=512 chain
    float su[8][4]  = {};   // running sequential block-combine

    // ---- prologue: stage tile 0 into buffer 0 ---------------------------
    {
        float* const A0 = smem;
        float* const B0 = smem + ASZ;
        async_lds16(&W[(size_t)br * OUT_SZ + o0 + bc], B0 + wv * 256);
        async_lds16(&W[(size_t)(8 + br) * OUT_SZ + o0 + bc], B0 + 512 + wv * 256);
        const float4 a0 = *reinterpret_cast<const float4*>(&x[aBase + 0]);
        const float4 a1 = *reinterpret_cast<const float4*>(&x[aBase + 4]);
        A0[(ak + 0) * BM + am] = a0.x;
        A0[(ak + 1) * BM + am] = a0.y;
        A0[(ak + 2) * BM + am] = a0.z;
        A0[(ak + 3) * BM + am] = a0.w;
        A0[(ak + 4) * BM + am] = a1.x;
        A0[(ak + 5) * BM + am] = a1.y;
        A0[(ak + 6) * BM + am] = a1.z;
        A0[(ak + 7) * BM + am] = a1.w;
    }
    __syncthreads();   // drains DMA (vmcnt 0) + A writes

    // ---- main loop: ONE barrier per K-step ------------------------------
    #pragma unroll 1
    for (int it = 0; it < NIT; ++it) {
        const float* const Ac = smem + (it & 1) * BUF;
        const float* const Bc = Ac + ASZ;
        float* const An = smem + ((it + 1) & 1) * BUF;
        float* const Bn = An + ASZ;

        // issue next tile's staging FIRST: B zero-reg DMA, A into regs
        float4 pa0, pa1;
        const bool pre = (it < NIT - 1);
        if (pre) {
            const int k0n = (it + 1) * BK;
            async_lds16(&W[(size_t)(k0n + br) * OUT_SZ + o0 + bc],
                        Bn + wv * 256);
            async_lds16(&W[(size_t)(k0n + 8 + br) * OUT_SZ + o0 + bc],
                        Bn + 512 + wv * 256);
            pa0 = *reinterpret_cast<const float4*>(&x[aBase + k0n]);
            pa1 = *reinterpret_cast<const float4*>(&x[aBase + k0n + 4]);
        }

        // KC=512 boundary (k0 = 512/1024/1536): sequential combine (FROZEN)
        if (it == 32 || it == 64 || it == 96) {
            #pragma unroll
            for (int i = 0; i < 8; ++i)
                #pragma unroll
                for (int j = 0; j < 4; ++j) {
                    su[i][j]  = __fadd_rn(su[i][j], acc[i][j]);
                    acc[i][j] = 0.0f;
                }
        }

        // ascending k; each acc[i][j] is one strict fmaf chain (FROZEN)
        #pragma unroll
        for (int k = 0; k < BK; ++k) {
            const float4 x0 = *reinterpret_cast<const float4*>(&Ac[k * BM + ty * 8]);
            const float4 x1 = *reinterpret_cast<const float4*>(&Ac[k * BM + ty * 8 + 4]);
            const float4 wf = *reinterpret_cast<const float4*>(&Bc[k * BN + tx * 4]);
            const float a[8] = {x0.x, x0.y, x0.z, x0.w, x1.x, x1.y, x1.z, x1.w};
            const float w[4] = {wf.x, wf.y, wf.z, wf.w};
            #pragma unroll
            for (int i = 0; i < 8; ++i)
                #pragma unroll
                for (int j = 0; j < 4; ++j)
                    acc[i][j] = __builtin_fmaf(a[i], w[j], acc[i][j]);
        }

        // write prefetched A into the other buffer (latency was hidden)
        if (pre) {
            An[(ak + 0) * BM + am] = pa0.x;
            An[(ak + 1) * BM + am] = pa0.y;
            An[(ak + 2) * BM + am] = pa0.z;
            An[(ak + 3) * BM + am] = pa0.w;
            An[(ak + 4) * BM + am] = pa1.x;
            An[(ak + 5) * BM + am] = pa1.y;
            An[(ak + 6) * BM + am] = pa1.z;
            An[(ak + 7) * BM + am] = pa1.w;
        }
        __syncthreads();   // implicit vmcnt(0): next tile's DMA complete
    }

    // final combine (FROZEN): y = su + acc
    #pragma unroll
    for (int i = 0; i < 8; ++i)
        #pragma unroll
        for (int j = 0; j < 4; ++j)
            su[i][j] = __fadd_rn(su[i][j], acc[i][j]);

    // ---- two-phase fused f64 scan (y-LDS = 32 rows, aliases staging) ----
    const int bl = tid >> 6;                // 0..1
    const int o  = tid & 63;                // 0..63
    const size_t plane  = (size_t)BATCH * OUT_SZ;
    const size_t outIdx = (size_t)(b0 + bl) * OUT_SZ + o0 + o;
    const double D = 1.0 / (1.0 + exp(-2.0));
    double u = 0.0;

    #pragma unroll
    for (int p = 0; p < 2; ++p) {
        __syncthreads();                    // prev phase/loop reads done
        if ((ty >> 2) == p) {               // ty 0-3 (p=0) or 4-7 (p=1)
            const int rb = ty * 8 - p * 32;
            #pragma unroll
            for (int i = 0; i < 8; ++i)
                #pragma unroll
                for (int j = 0; j < 4; ++j)
                    smem[(rb + i) * YSTR + tx * 4 + j] = su[i][j];
        }
        __syncthreads();
        #pragma unroll
        for (int tt = 0; tt < 16; ++tt) {   // local row: m - 32p = 2*tt+bl
            const int t = p * 16 + tt;
            const double y  = (double)smem[(tt * 2 + bl) * YSTR + o];
            const double un = __dadd_rn(__dmul_rn(D, u), y);
            const double s  = (un >= 1.0) ? 1.0 : 0.0;
            u = __dsub_rn(un, s);
            out[(size_t)t * plane + outIdx] = (float)s;
        }
    }
}

// -------------------------------------------------------------------------
extern "C" void kernel_launch(void* const* d_in, const int* in_sizes, int n_in,
                              void* d_out, int out_size, void* d_ws, size_t ws_size,
                              hipStream_t stream) {
    const float* x = (const float*)d_in[0];   // [T, B, IN] f32
    const float* W = (const float*)d_in[1];   // [IN, OUT] f32
    float* out     = (float*)d_out;           // [T, B, OUT] f32 spikes

    dim3 grid(OUT_SZ / 64, BATCH / 2);        // 32 x 64 = 2048 blocks (8/CU)
    Approx_OTPE_67181878444197_kernel<<<grid, 128, 0, stream>>>(x, W, out);
}

// Round 25
// 464.236 us; speedup vs baseline: 1.4406x; 1.4406x over previous
//
#include <hip/hip_runtime.h>
#include <math.h>

constexpr int T_STEPS = 32;
constexpr int BATCH   = 128;
constexpr int IN_SZ   = 2048;   // K
constexpr int OUT_SZ  = 2048;   // N

// -------------------------------------------------------------------------
// FROZEN reference arithmetic (verified r14, absmax 0.0 r15-r24):
//   GEMM: f32, KC=512 uniform K-blocks; per element a fresh ascending-k
//         fmaf chain per block, f32 sequential block-combine.
//   Scan: f64 state, un = D*u + y (sep mul/add), s = (un>=1), u = un-s,
//         D = 1/(1+exp(-2)) in f64.
// r25 = r16 (best: 479 us, VGPR 80, no spill) with BK=32: halves the
// barrier/vmcnt-drain count (the measured 42% idle), 1024 FMA-cycles per
// barrier pair. 128x64 tile, 8x4 micro, 256 threads, simple 2-barrier
// staging (pipeline variants all VGPR-pathological, abandoned).
// LDS 33.3 KB (24 KB staging aliased under y-buffer) -> 4 blocks/CU.
// Per-element chain arithmetic bit-identical to r15-r24.
// -------------------------------------------------------------------------
__global__ __launch_bounds__(256, 1) void Approx_OTPE_67181878444197_kernel(
        const float* __restrict__ x,
        const float* __restrict__ W,
        float* __restrict__ out) {
    constexpr int BK = 32, BM = 128, BN = 64;
    constexpr int YSTR = BN + 1;            // 65
    constexpr int YSZ  = BM * YSTR;         // 8320 floats = 33.3 KB

    __shared__ float smem[YSZ];             // staging (6144 f) aliases y
    float* const As = smem;                 // [BK][BM] k-major
    float* const Bs = smem + BK * BM;       // [BK][BN]

    const int o0  = blockIdx.x * BN;
    const int b0  = blockIdx.y * 4;
    const int tid = threadIdx.x;            // 0..255
    const int ty  = tid >> 4;               // 0..15 -> 8-row group
    const int tx  = tid & 15;               // 0..15 -> 4-col group

    // A staging: m_local = tid>>1 (0..127), k-half = (tid&1)*16
    // m_local = t*4 + bl -> global row t*BATCH + (b0+bl)
    const int am = tid >> 1;
    const int ak = (tid & 1) * 16;
    const int at = am >> 2;
    const int ab = am & 3;
    const size_t aBase = ((size_t)at * BATCH + (size_t)(b0 + ab)) * IN_SZ + ak;

    // B staging: rows br and br+16 (k), col bc, one float4 each
    const int br = tid >> 4;                // 0..15
    const int bc = (tid & 15) * 4;          // 0..60

    float acc[8][4] = {};   // current KC=512 chain
    float su[8][4]  = {};   // running sequential block-combine

    #pragma unroll 1
    for (int it = 0; it < IN_SZ / BK; ++it) {
        const int k0 = it * BK;
        // issue global loads at top (overlap previous compute + barriers)
        const float4 a0 = *reinterpret_cast<const float4*>(&x[aBase + k0]);
        const float4 a1 = *reinterpret_cast<const float4*>(&x[aBase + k0 + 4]);
        const float4 a2 = *reinterpret_cast<const float4*>(&x[aBase + k0 + 8]);
        const float4 a3 = *reinterpret_cast<const float4*>(&x[aBase + k0 + 12]);
        const float4 v0 = *reinterpret_cast<const float4*>(
            &W[(size_t)(k0 + br) * OUT_SZ + o0 + bc]);
        const float4 v1 = *reinterpret_cast<const float4*>(
            &W[(size_t)(k0 + 16 + br) * OUT_SZ + o0 + bc]);

        // KC=512 boundary (k0 = 512/1024/1536): sequential combine (FROZEN)
        if (it == 16 || it == 32 || it == 48) {
            #pragma unroll
            for (int i = 0; i < 8; ++i)
                #pragma unroll
                for (int j = 0; j < 4; ++j) {
                    su[i][j]  = __fadd_rn(su[i][j], acc[i][j]);
                    acc[i][j] = 0.0f;
                }
        }

        __syncthreads();   // previous iteration's LDS reads done
        As[(ak +  0) * BM + am] = a0.x;
        As[(ak +  1) * BM + am] = a0.y;
        As[(ak +  2) * BM + am] = a0.z;
        As[(ak +  3) * BM + am] = a0.w;
        As[(ak +  4) * BM + am] = a1.x;
        As[(ak +  5) * BM + am] = a1.y;
        As[(ak +  6) * BM + am] = a1.z;
        As[(ak +  7) * BM + am] = a1.w;
        As[(ak +  8) * BM + am] = a2.x;
        As[(ak +  9) * BM + am] = a2.y;
        As[(ak + 10) * BM + am] = a2.z;
        As[(ak + 11) * BM + am] = a2.w;
        As[(ak + 12) * BM + am] = a3.x;
        As[(ak + 13) * BM + am] = a3.y;
        As[(ak + 14) * BM + am] = a3.z;
        As[(ak + 15) * BM + am] = a3.w;
        *reinterpret_cast<float4*>(&Bs[br * BN + bc])        = v0;
        *reinterpret_cast<float4*>(&Bs[(br + 16) * BN + bc]) = v1;
        __syncthreads();

        // ascending k; each acc[i][j] is one strict fmaf chain (FROZEN)
        #pragma unroll
        for (int k = 0; k < BK; ++k) {
            const float4 x0 = *reinterpret_cast<const float4*>(&As[k * BM + ty * 8]);
            const float4 x1 = *reinterpret_cast<const float4*>(&As[k * BM + ty * 8 + 4]);
            const float4 wf = *reinterpret_cast<const float4*>(&Bs[k * BN + tx * 4]);
            const float a[8] = {x0.x, x0.y, x0.z, x0.w, x1.x, x1.y, x1.z, x1.w};
            const float w[4] = {wf.x, wf.y, wf.z, wf.w};
            #pragma unroll
            for (int i = 0; i < 8; ++i)
                #pragma unroll
                for (int j = 0; j < 4; ++j)
                    acc[i][j] = __builtin_fmaf(a[i], w[j], acc[i][j]);
        }
    }

    // final combine (FROZEN) + y-transpose dump (staging region is dead)
    __syncthreads();
    #pragma unroll
    for (int i = 0; i < 8; ++i)
        #pragma unroll
        for (int j = 0; j < 4; ++j)
            smem[(ty * 8 + i) * YSTR + tx * 4 + j] = __fadd_rn(su[i][j], acc[i][j]);
    __syncthreads();

    // fused f64 scan: all 256 threads, one (bl, o) pair each
    {
        const int bl = tid >> 6;            // 0..3
        const int o  = tid & 63;            // 0..63
        const size_t plane  = (size_t)BATCH * OUT_SZ;
        const size_t outIdx = (size_t)(b0 + bl) * OUT_SZ + o0 + o;

        const double D = 1.0 / (1.0 + exp(-2.0));
        double u = 0.0;
        #pragma unroll
        for (int t = 0; t < T_STEPS; ++t) {
            const double y  = (double)smem[(t * 4 + bl) * YSTR + o];
            const double un = __dadd_rn(__dmul_rn(D, u), y);
            const double s  = (un >= 1.0) ? 1.0 : 0.0;
            u = __dsub_rn(un, s);
            out[(size_t)t * plane + outIdx] = (float)s;
        }
    }
}

// -------------------------------------------------------------------------
extern "C" void kernel_launch(void* const* d_in, const int* in_sizes, int n_in,
                              void* d_out, int out_size, void* d_ws, size_t ws_size,
                              hipStream_t stream) {
    const float* x = (const float*)d_in[0];   // [T, B, IN] f32
    const float* W = (const float*)d_in[1];   // [IN, OUT] f32
    float* out     = (float*)d_out;           // [T, B, OUT] f32 spikes

    dim3 grid(OUT_SZ / 64, BATCH / 4);        // 32 x 32 = 1024 blocks (4/CU)
    Approx_OTPE_67181878444197_kernel<<<grid, 256, 0, stream>>>(x, W, out);
}

// Round 26
// 435.349 us; speedup vs baseline: 1.5362x; 1.0664x over previous
//
#include <hip/hip_runtime.h>
#include <math.h>

constexpr int T_STEPS = 32;
constexpr int BATCH   = 128;
constexpr int IN_SZ   = 2048;   // K
constexpr int OUT_SZ  = 2048;   // N
constexpr int M_ROWS  = T_STEPS * BATCH;  // 4096

// -------------------------------------------------------------------------
// FROZEN reference arithmetic (verified r14, absmax 0.0 r15-r25):
//   GEMM: f32, KC=512 uniform K-blocks; per element a fresh ascending-k
//         fmaf chain per block; combine ((((0+c0)+c1)+c2)+c3) in f32.
//   Scan: f64 state, un = D*u + y (sep mul/add), s = (un>=1), u = un-s,
//         D = 1/(1+exp(-2)) in f64.
// r26: split-K x4. Each KC=512 chain computed by its own block (grid.z=4):
// no su registers, no flush branches -> lower VGPR + 4x blocks (TLP).
// Partials in d_ws [4][4096][2048] f32; combine+scan kernel applies the
// frozen combine order then the frozen f64 scan. Host falls back to the
// r25 single-kernel path if ws_size < 134 MB.
// -------------------------------------------------------------------------

// ---- split-K GEMM: one KC=512 chain per block ---------------------------
__global__ __launch_bounds__(256, 1) void Approx_OTPE_67181878444197_kernel(
        const float* __restrict__ x,
        const float* __restrict__ W,
        float* __restrict__ ws) {
    constexpr int BK = 32, BM = 128, BN = 64;

    __shared__ float As[BK * BM];           // k-major [k][m]
    __shared__ float Bs[BK * BN];           // [k][n]

    const int o0  = blockIdx.x * BN;
    const int m0  = blockIdx.y * BM;
    const int z   = blockIdx.z;             // KC block 0..3
    const int kz  = z * 512;
    const int tid = threadIdx.x;            // 0..255
    const int ty  = tid >> 4;               // 0..15
    const int tx  = tid & 15;               // 0..15

    // A staging: m_local = tid>>1 (0..127), k-half = (tid&1)*16
    const int am = tid >> 1;
    const int ak = (tid & 1) * 16;
    const size_t aBase = (size_t)(m0 + am) * IN_SZ + kz + ak;

    // B staging: rows br, br+16; col bc (float4 each)
    const int br = tid >> 4;
    const int bc = (tid & 15) * 4;

    float acc[8][4] = {};   // single KC=512 ascending-k chain (FROZEN)

    #pragma unroll 1
    for (int it = 0; it < 512 / BK; ++it) {
        const int k0 = it * BK;
        const float4 a0 = *reinterpret_cast<const float4*>(&x[aBase + k0]);
        const float4 a1 = *reinterpret_cast<const float4*>(&x[aBase + k0 + 4]);
        const float4 a2 = *reinterpret_cast<const float4*>(&x[aBase + k0 + 8]);
        const float4 a3 = *reinterpret_cast<const float4*>(&x[aBase + k0 + 12]);
        const float4 v0 = *reinterpret_cast<const float4*>(
            &W[(size_t)(kz + k0 + br) * OUT_SZ + o0 + bc]);
        const float4 v1 = *reinterpret_cast<const float4*>(
            &W[(size_t)(kz + k0 + 16 + br) * OUT_SZ + o0 + bc]);

        __syncthreads();
        As[(ak +  0) * BM + am] = a0.x;
        As[(ak +  1) * BM + am] = a0.y;
        As[(ak +  2) * BM + am] = a0.z;
        As[(ak +  3) * BM + am] = a0.w;
        As[(ak +  4) * BM + am] = a1.x;
        As[(ak +  5) * BM + am] = a1.y;
        As[(ak +  6) * BM + am] = a1.z;
        As[(ak +  7) * BM + am] = a1.w;
        As[(ak +  8) * BM + am] = a2.x;
        As[(ak +  9) * BM + am] = a2.y;
        As[(ak + 10) * BM + am] = a2.z;
        As[(ak + 11) * BM + am] = a2.w;
        As[(ak + 12) * BM + am] = a3.x;
        As[(ak + 13) * BM + am] = a3.y;
        As[(ak + 14) * BM + am] = a3.z;
        As[(ak + 15) * BM + am] = a3.w;
        *reinterpret_cast<float4*>(&Bs[br * BN + bc])        = v0;
        *reinterpret_cast<float4*>(&Bs[(br + 16) * BN + bc]) = v1;
        __syncthreads();

        #pragma unroll
        for (int k = 0; k < BK; ++k) {
            const float4 x0 = *reinterpret_cast<const float4*>(&As[k * BM + ty * 8]);
            const float4 x1 = *reinterpret_cast<const float4*>(&As[k * BM + ty * 8 + 4]);
            const float4 wf = *reinterpret_cast<const float4*>(&Bs[k * BN + tx * 4]);
            const float a[8] = {x0.x, x0.y, x0.z, x0.w, x1.x, x1.y, x1.z, x1.w};
            const float w[4] = {wf.x, wf.y, wf.z, wf.w};
            #pragma unroll
            for (int i = 0; i < 8; ++i)
                #pragma unroll
                for (int j = 0; j < 4; ++j)
                    acc[i][j] = __builtin_fmaf(a[i], w[j], acc[i][j]);
        }
    }

    // write partials (coalesced float4 per row)
    float* const wz = ws + (size_t)z * M_ROWS * OUT_SZ;
    #pragma unroll
    for (int i = 0; i < 8; ++i) {
        float4 v;
        v.x = acc[i][0]; v.y = acc[i][1]; v.z = acc[i][2]; v.w = acc[i][3];
        *reinterpret_cast<float4*>(
            &wz[(size_t)(m0 + ty * 8 + i) * OUT_SZ + o0 + tx * 4]) = v;
    }
}

// ---- combine (frozen order) + frozen f64 scan ---------------------------
__global__ __launch_bounds__(256, 1) void snn_combine_scan(
        const float* __restrict__ ws, float* __restrict__ out) {
    const int gid = blockIdx.x * 256 + threadIdx.x;   // 0..B*OUT-1
    const int b   = gid >> 11;                        // /2048
    const int o   = gid & 2047;
    const size_t plane = (size_t)BATCH * OUT_SZ;
    constexpr size_t ZS = (size_t)M_ROWS * OUT_SZ;

    const double D = 1.0 / (1.0 + exp(-2.0));
    double u = 0.0;
    #pragma unroll 1
    for (int t = 0; t < T_STEPS; ++t) {
        const size_t r = (size_t)(t * BATCH + b) * OUT_SZ + o;
        const float p0 = ws[r];
        const float p1 = ws[r + ZS];
        const float p2 = ws[r + 2 * ZS];
        const float p3 = ws[r + 3 * ZS];
        // FROZEN combine: ((((0+c0)+c1)+c2)+c3)
        float y = __fadd_rn(0.0f, p0);
        y = __fadd_rn(y, p1);
        y = __fadd_rn(y, p2);
        y = __fadd_rn(y, p3);
        // FROZEN f64 scan step
        const double un = __dadd_rn(__dmul_rn(D, u), (double)y);
        const double s  = (un >= 1.0) ? 1.0 : 0.0;
        u = __dsub_rn(un, s);
        out[(size_t)t * plane + gid] = (float)s;
    }
}

// ---- fallback: r25 fused kernel (absmax 0.0, 464 us) --------------------
__global__ __launch_bounds__(256, 1) void snn_fused_r25(
        const float* __restrict__ x,
        const float* __restrict__ W,
        float* __restrict__ out) {
    constexpr int BK = 32, BM = 128, BN = 64;
    constexpr int YSTR = BN + 1;
    constexpr int YSZ  = BM * YSTR;

    __shared__ float smem[YSZ];
    float* const As = smem;
    float* const Bs = smem + BK * BM;

    const int o0  = blockIdx.x * BN;
    const int b0  = blockIdx.y * 4;
    const int tid = threadIdx.x;
    const int ty  = tid >> 4;
    const int tx  = tid & 15;

    const int am = tid >> 1;
    const int ak = (tid & 1) * 16;
    const int at = am >> 2;
    const int ab = am & 3;
    const size_t aBase = ((size_t)at * BATCH + (size_t)(b0 + ab)) * IN_SZ + ak;

    const int br = tid >> 4;
    const int bc = (tid & 15) * 4;

    float acc[8][4] = {};
    float su[8][4]  = {};

    #pragma unroll 1
    for (int it = 0; it < IN_SZ / BK; ++it) {
        const int k0 = it * BK;
        const float4 a0 = *reinterpret_cast<const float4*>(&x[aBase + k0]);
        const float4 a1 = *reinterpret_cast<const float4*>(&x[aBase + k0 + 4]);
        const float4 a2 = *reinterpret_cast<const float4*>(&x[aBase + k0 + 8]);
        const float4 a3 = *reinterpret_cast<const float4*>(&x[aBase + k0 + 12]);
        const float4 v0 = *reinterpret_cast<const float4*>(
            &W[(size_t)(k0 + br) * OUT_SZ + o0 + bc]);
        const float4 v1 = *reinterpret_cast<const float4*>(
            &W[(size_t)(k0 + 16 + br) * OUT_SZ + o0 + bc]);

        if (it == 16 || it == 32 || it == 48) {
            #pragma unroll
            for (int i = 0; i < 8; ++i)
                #pragma unroll
                for (int j = 0; j < 4; ++j) {
                    su[i][j]  = __fadd_rn(su[i][j], acc[i][j]);
                    acc[i][j] = 0.0f;
                }
        }

        __syncthreads();
        As[(ak +  0) * BM + am] = a0.x;
        As[(ak +  1) * BM + am] = a0.y;
        As[(ak +  2) * BM + am] = a0.z;
        As[(ak +  3) * BM + am] = a0.w;
        As[(ak +  4) * BM + am] = a1.x;
        As[(ak +  5) * BM + am] = a1.y;
        As[(ak +  6) * BM + am] = a1.z;
        As[(ak +  7) * BM + am] = a1.w;
        As[(ak +  8) * BM + am] = a2.x;
        As[(ak +  9) * BM + am] = a2.y;
        As[(ak + 10) * BM + am] = a2.z;
        As[(ak + 11) * BM + am] = a2.w;
        As[(ak + 12) * BM + am] = a3.x;
        As[(ak + 13) * BM + am] = a3.y;
        As[(ak + 14) * BM + am] = a3.z;
        As[(ak + 15) * BM + am] = a3.w;
        *reinterpret_cast<float4*>(&Bs[br * BN + bc])        = v0;
        *reinterpret_cast<float4*>(&Bs[(br + 16) * BN + bc]) = v1;
        __syncthreads();

        #pragma unroll
        for (int k = 0; k < BK; ++k) {
            const float4 x0 = *reinterpret_cast<const float4*>(&As[k * BM + ty * 8]);
            const float4 x1 = *reinterpret_cast<const float4*>(&As[k * BM + ty * 8 + 4]);
            const float4 wf = *reinterpret_cast<const float4*>(&Bs[k * BN + tx * 4]);
            const float a[8] = {x0.x, x0.y, x0.z, x0.w, x1.x, x1.y, x1.z, x1.w};
            const float w[4] = {wf.x, wf.y, wf.z, wf.w};
            #pragma unroll
            for (int i = 0; i < 8; ++i)
                #pragma unroll
                for (int j = 0; j < 4; ++j)
                    acc[i][j] = __builtin_fmaf(a[i], w[j], acc[i][j]);
        }
    }

    __syncthreads();
    #pragma unroll
    for (int i = 0; i < 8; ++i)
        #pragma unroll
        for (int j = 0; j < 4; ++j)
            smem[(ty * 8 + i) * YSTR + tx * 4 + j] = __fadd_rn(su[i][j], acc[i][j]);
    __syncthreads();

    {
        const int bl = tid >> 6;
        const int o  = tid & 63;
        const size_t plane  = (size_t)BATCH * OUT_SZ;
        const size_t outIdx = (size_t)(b0 + bl) * OUT_SZ + o0 + o;

        const double D = 1.0 / (1.0 + exp(-2.0));
        double u = 0.0;
        #pragma unroll
        for (int t = 0; t < T_STEPS; ++t) {
            const double y  = (double)smem[(t * 4 + bl) * YSTR + o];
            const double un = __dadd_rn(__dmul_rn(D, u), y);
            const double s  = (un >= 1.0) ? 1.0 : 0.0;
            u = __dsub_rn(un, s);
            out[(size_t)t * plane + outIdx] = (float)s;
        }
    }
}

// -------------------------------------------------------------------------
extern "C" void kernel_launch(void* const* d_in, const int* in_sizes, int n_in,
                              void* d_out, int out_size, void* d_ws, size_t ws_size,
                              hipStream_t stream) {
    const float* x = (const float*)d_in[0];   // [T, B, IN] f32
    const float* W = (const float*)d_in[1];   // [IN, OUT] f32
    float* out     = (float*)d_out;           // [T, B, OUT] f32 spikes

    const size_t wsNeeded = (size_t)4 * M_ROWS * OUT_SZ * sizeof(float);
    if (ws_size >= wsNeeded) {
        dim3 g1(OUT_SZ / 64, M_ROWS / 128, 4);    // 32 x 32 x 4 = 4096 blocks
        Approx_OTPE_67181878444197_kernel<<<g1, 256, 0, stream>>>(
            x, W, (float*)d_ws);
        snn_combine_scan<<<(BATCH * OUT_SZ) / 256, 256, 0, stream>>>(
            (const float*)d_ws, out);
    } else {
        dim3 grid(OUT_SZ / 64, BATCH / 4);        // r25 fallback
        snn_fused_r25<<<grid, 256, 0, stream>>>(x, W, out);
    }
}

// Round 27
// 414.854 us; speedup vs baseline: 1.6121x; 1.0494x over previous
//
#include <hip/hip_runtime.h>
#include <math.h>

constexpr int T_STEPS = 32;
constexpr int BATCH   = 128;
constexpr int IN_SZ   = 2048;   // K
constexpr int OUT_SZ  = 2048;   // N
constexpr int M_ROWS  = T_STEPS * BATCH;  // 4096

// -------------------------------------------------------------------------
// FROZEN reference arithmetic (verified r14, absmax 0.0 r15-r26):
//   GEMM: f32, KC=512 uniform K-blocks; per element a fresh ascending-k
//         fmaf chain per block; combine ((((0+c0)+c1)+c2)+c3) in f32.
//   Scan: f64 state, un = D*u + y (sep mul/add), s = (un>=1), u = un-s,
//         D = 1/(1+exp(-2)) in f64.
// r27: split-K x4 (r26: VGPR 44, VALU 80%, 435 us) with an 8x8 micro-tile,
// now register-feasible without su: 128x128 tile, 64 FMA : 4 ds_read_b128
// per k (1.4x fewer staging instrs/FLOP), A global re-reads halved.
// LDS 32 KB, grid 16x32x4 = 2048 blocks. Combine+scan kernel unchanged.
// Per-element chain arithmetic bit-identical to r15-r26.
// -------------------------------------------------------------------------

// ---- split-K GEMM: one KC=512 chain per block, 8x8 micro ----------------
__global__ __launch_bounds__(256, 1) void Approx_OTPE_67181878444197_kernel(
        const float* __restrict__ x,
        const float* __restrict__ W,
        float* __restrict__ ws) {
    constexpr int BK = 32, BM = 128, BN = 128;

    __shared__ float As[BK * BM];           // k-major [k][m]  16 KB
    __shared__ float Bs[BK * BN];           // [k][n]          16 KB

    const int o0  = blockIdx.x * BN;
    const int m0  = blockIdx.y * BM;
    const int z   = blockIdx.z;             // KC block 0..3
    const int kz  = z * 512;
    const int tid = threadIdx.x;            // 0..255
    const int ty  = tid >> 4;               // 0..15 -> 8-row group
    const int tx  = tid & 15;               // 0..15 -> 8-col group

    // A staging: m_local = tid>>1 (0..127), k-half = (tid&1)*16
    const int am = tid >> 1;
    const int ak = (tid & 1) * 16;
    const size_t aBase = (size_t)(m0 + am) * IN_SZ + kz + ak;

    // B staging: rows br, br+16; cols bc, bc+4 (four float4 per thread)
    const int br = tid >> 4;                // 0..15
    const int bc = (tid & 15) * 8;          // 0..120

    float acc[8][8] = {};   // single KC=512 ascending-k chain (FROZEN)

    #pragma unroll 1
    for (int it = 0; it < 512 / BK; ++it) {
        const int k0 = it * BK;
        const float4 a0 = *reinterpret_cast<const float4*>(&x[aBase + k0]);
        const float4 a1 = *reinterpret_cast<const float4*>(&x[aBase + k0 + 4]);
        const float4 a2 = *reinterpret_cast<const float4*>(&x[aBase + k0 + 8]);
        const float4 a3 = *reinterpret_cast<const float4*>(&x[aBase + k0 + 12]);
        const float4 v0 = *reinterpret_cast<const float4*>(
            &W[(size_t)(kz + k0 + br) * OUT_SZ + o0 + bc]);
        const float4 v1 = *reinterpret_cast<const float4*>(
            &W[(size_t)(kz + k0 + br) * OUT_SZ + o0 + bc + 4]);
        const float4 v2 = *reinterpret_cast<const float4*>(
            &W[(size_t)(kz + k0 + 16 + br) * OUT_SZ + o0 + bc]);
        const float4 v3 = *reinterpret_cast<const float4*>(
            &W[(size_t)(kz + k0 + 16 + br) * OUT_SZ + o0 + bc + 4]);

        __syncthreads();
        As[(ak +  0) * BM + am] = a0.x;
        As[(ak +  1) * BM + am] = a0.y;
        As[(ak +  2) * BM + am] = a0.z;
        As[(ak +  3) * BM + am] = a0.w;
        As[(ak +  4) * BM + am] = a1.x;
        As[(ak +  5) * BM + am] = a1.y;
        As[(ak +  6) * BM + am] = a1.z;
        As[(ak +  7) * BM + am] = a1.w;
        As[(ak +  8) * BM + am] = a2.x;
        As[(ak +  9) * BM + am] = a2.y;
        As[(ak + 10) * BM + am] = a2.z;
        As[(ak + 11) * BM + am] = a2.w;
        As[(ak + 12) * BM + am] = a3.x;
        As[(ak + 13) * BM + am] = a3.y;
        As[(ak + 14) * BM + am] = a3.z;
        As[(ak + 15) * BM + am] = a3.w;
        *reinterpret_cast<float4*>(&Bs[br * BN + bc])            = v0;
        *reinterpret_cast<float4*>(&Bs[br * BN + bc + 4])        = v1;
        *reinterpret_cast<float4*>(&Bs[(br + 16) * BN + bc])     = v2;
        *reinterpret_cast<float4*>(&Bs[(br + 16) * BN + bc + 4]) = v3;
        __syncthreads();

        // ascending k; each acc[i][j] is one strict fmaf chain (FROZEN)
        #pragma unroll
        for (int k = 0; k < BK; ++k) {
            const float4 x0 = *reinterpret_cast<const float4*>(&As[k * BM + ty * 8]);
            const float4 x1 = *reinterpret_cast<const float4*>(&As[k * BM + ty * 8 + 4]);
            const float4 w0 = *reinterpret_cast<const float4*>(&Bs[k * BN + tx * 8]);
            const float4 w1 = *reinterpret_cast<const float4*>(&Bs[k * BN + tx * 8 + 4]);
            const float a[8] = {x0.x, x0.y, x0.z, x0.w, x1.x, x1.y, x1.z, x1.w};
            const float w[8] = {w0.x, w0.y, w0.z, w0.w, w1.x, w1.y, w1.z, w1.w};
            #pragma unroll
            for (int i = 0; i < 8; ++i)
                #pragma unroll
                for (int j = 0; j < 8; ++j)
                    acc[i][j] = __builtin_fmaf(a[i], w[j], acc[i][j]);
        }
    }

    // write partials (two coalesced float4 per row)
    float* const wz = ws + (size_t)z * M_ROWS * OUT_SZ;
    #pragma unroll
    for (int i = 0; i < 8; ++i) {
        float4 v;
        v.x = acc[i][0]; v.y = acc[i][1]; v.z = acc[i][2]; v.w = acc[i][3];
        float4 v2;
        v2.x = acc[i][4]; v2.y = acc[i][5]; v2.z = acc[i][6]; v2.w = acc[i][7];
        float* const row = &wz[(size_t)(m0 + ty * 8 + i) * OUT_SZ + o0 + tx * 8];
        *reinterpret_cast<float4*>(row)     = v;
        *reinterpret_cast<float4*>(row + 4) = v2;
    }
}

// ---- combine (frozen order) + frozen f64 scan ---------------------------
__global__ __launch_bounds__(256, 1) void snn_combine_scan(
        const float* __restrict__ ws, float* __restrict__ out) {
    const int gid = blockIdx.x * 256 + threadIdx.x;   // 0..B*OUT-1
    const int b   = gid >> 11;                        // /2048
    const int o   = gid & 2047;
    const size_t plane = (size_t)BATCH * OUT_SZ;
    constexpr size_t ZS = (size_t)M_ROWS * OUT_SZ;

    const double D = 1.0 / (1.0 + exp(-2.0));
    double u = 0.0;
    #pragma unroll 1
    for (int t = 0; t < T_STEPS; ++t) {
        const size_t r = (size_t)(t * BATCH + b) * OUT_SZ + o;
        const float p0 = ws[r];
        const float p1 = ws[r + ZS];
        const float p2 = ws[r + 2 * ZS];
        const float p3 = ws[r + 3 * ZS];
        // FROZEN combine: ((((0+c0)+c1)+c2)+c3)
        float y = __fadd_rn(0.0f, p0);
        y = __fadd_rn(y, p1);
        y = __fadd_rn(y, p2);
        y = __fadd_rn(y, p3);
        // FROZEN f64 scan step
        const double un = __dadd_rn(__dmul_rn(D, u), (double)y);
        const double s  = (un >= 1.0) ? 1.0 : 0.0;
        u = __dsub_rn(un, s);
        out[(size_t)t * plane + gid] = (float)s;
    }
}

// ---- fallback: r25 fused kernel (absmax 0.0, 464 us) --------------------
__global__ __launch_bounds__(256, 1) void snn_fused_r25(
        const float* __restrict__ x,
        const float* __restrict__ W,
        float* __restrict__ out) {
    constexpr int BK = 32, BM = 128, BN = 64;
    constexpr int YSTR = BN + 1;
    constexpr int YSZ  = BM * YSTR;

    __shared__ float smem[YSZ];
    float* const As = smem;
    float* const Bs = smem + BK * BM;

    const int o0  = blockIdx.x * BN;
    const int b0  = blockIdx.y * 4;
    const int tid = threadIdx.x;
    const int ty  = tid >> 4;
    const int tx  = tid & 15;

    const int am = tid >> 1;
    const int ak = (tid & 1) * 16;
    const int at = am >> 2;
    const int ab = am & 3;
    const size_t aBase = ((size_t)at * BATCH + (size_t)(b0 + ab)) * IN_SZ + ak;

    const int br = tid >> 4;
    const int bc = (tid & 15) * 4;

    float acc[8][4] = {};
    float su[8][4]  = {};

    #pragma unroll 1
    for (int it = 0; it < IN_SZ / BK; ++it) {
        const int k0 = it * BK;
        const float4 a0 = *reinterpret_cast<const float4*>(&x[aBase + k0]);
        const float4 a1 = *reinterpret_cast<const float4*>(&x[aBase + k0 + 4]);
        const float4 a2 = *reinterpret_cast<const float4*>(&x[aBase + k0 + 8]);
        const float4 a3 = *reinterpret_cast<const float4*>(&x[aBase + k0 + 12]);
        const float4 v0 = *reinterpret_cast<const float4*>(
            &W[(size_t)(k0 + br) * OUT_SZ + o0 + bc]);
        const float4 v1 = *reinterpret_cast<const float4*>(
            &W[(size_t)(k0 + 16 + br) * OUT_SZ + o0 + bc]);

        if (it == 16 || it == 32 || it == 48) {
            #pragma unroll
            for (int i = 0; i < 8; ++i)
                #pragma unroll
                for (int j = 0; j < 4; ++j) {
                    su[i][j]  = __fadd_rn(su[i][j], acc[i][j]);
                    acc[i][j] = 0.0f;
                }
        }

        __syncthreads();
        As[(ak +  0) * BM + am] = a0.x;
        As[(ak +  1) * BM + am] = a0.y;
        As[(ak +  2) * BM + am] = a0.z;
        As[(ak +  3) * BM + am] = a0.w;
        As[(ak +  4) * BM + am] = a1.x;
        As[(ak +  5) * BM + am] = a1.y;
        As[(ak +  6) * BM + am] = a1.z;
        As[(ak +  7) * BM + am] = a1.w;
        As[(ak +  8) * BM + am] = a2.x;
        As[(ak +  9) * BM + am] = a2.y;
        As[(ak + 10) * BM + am] = a2.z;
        As[(ak + 11) * BM + am] = a2.w;
        As[(ak + 12) * BM + am] = a3.x;
        As[(ak + 13) * BM + am] = a3.y;
        As[(ak + 14) * BM + am] = a3.z;
        As[(ak + 15) * BM + am] = a3.w;
        *reinterpret_cast<float4*>(&Bs[br * BN + bc])        = v0;
        *reinterpret_cast<float4*>(&Bs[(br + 16) * BN + bc]) = v1;
        __syncthreads();

        #pragma unroll
        for (int k = 0; k < BK; ++k) {
            const float4 x0 = *reinterpret_cast<const float4*>(&As[k * BM + ty * 8]);
            const float4 x1 = *reinterpret_cast<const float4*>(&As[k * BM + ty * 8 + 4]);
            const float4 wf = *reinterpret_cast<const float4*>(&Bs[k * BN + tx * 4]);
            const float a[8] = {x0.x, x0.y, x0.z, x0.w, x1.x, x1.y, x1.z, x1.w};
            const float w[4] = {wf.x, wf.y, wf.z, wf.w};
            #pragma unroll
            for (int i = 0; i < 8; ++i)
                #pragma unroll
                for (int j = 0; j < 4; ++j)
                    acc[i][j] = __builtin_fmaf(a[i], w[j], acc[i][j]);
        }
    }

    __syncthreads();
    #pragma unroll
    for (int i = 0; i < 8; ++i)
        #pragma unroll
        for (int j = 0; j < 4; ++j)
            smem[(ty * 8 + i) * YSTR + tx * 4 + j] = __fadd_rn(su[i][j], acc[i][j]);
    __syncthreads();

    {
        const int bl = tid >> 6;
        const int o  = tid & 63;
        const size_t plane  = (size_t)BATCH * OUT_SZ;
        const size_t outIdx = (size_t)(b0 + bl) * OUT_SZ + o0 + o;

        const double D = 1.0 / (1.0 + exp(-2.0));
        double u = 0.0;
        #pragma unroll
        for (int t = 0; t < T_STEPS; ++t) {
            const double y  = (double)smem[(t * 4 + bl) * YSTR + o];
            const double un = __dadd_rn(__dmul_rn(D, u), y);
            const double s  = (un >= 1.0) ? 1.0 : 0.0;
            u = __dsub_rn(un, s);
            out[(size_t)t * plane + outIdx] = (float)s;
        }
    }
}

// -------------------------------------------------------------------------
extern "C" void kernel_launch(void* const* d_in, const int* in_sizes, int n_in,
                              void* d_out, int out_size, void* d_ws, size_t ws_size,
                              hipStream_t stream) {
    const float* x = (const float*)d_in[0];   // [T, B, IN] f32
    const float* W = (const float*)d_in[1];   // [IN, OUT] f32
    float* out     = (float*)d_out;           // [T, B, OUT] f32 spikes

    const size_t wsNeeded = (size_t)4 * M_ROWS * OUT_SZ * sizeof(float);
    if (ws_size >= wsNeeded) {
        dim3 g1(OUT_SZ / 128, M_ROWS / 128, 4);   // 16 x 32 x 4 = 2048 blocks
        Approx_OTPE_67181878444197_kernel<<<g1, 256, 0, stream>>>(
            x, W, (float*)d_ws);
        snn_combine_scan<<<(BATCH * OUT_SZ) / 256, 256, 0, stream>>>(
            (const float*)d_ws, out);
    } else {
        dim3 grid(OUT_SZ / 64, BATCH / 4);        // r25 fallback
        snn_fused_r25<<<grid, 256, 0, stream>>>(x, W, out);
    }
}

// Round 28
// 407.577 us; speedup vs baseline: 1.6409x; 1.0179x over previous
//
#include <hip/hip_runtime.h>
#include <math.h>

constexpr int T_STEPS = 32;
constexpr int BATCH   = 128;
constexpr int IN_SZ   = 2048;   // K
constexpr int OUT_SZ  = 2048;   // N
constexpr int M_ROWS  = T_STEPS * BATCH;  // 4096

// -------------------------------------------------------------------------
// FROZEN reference arithmetic (verified r14, absmax 0.0 r15-r27):
//   GEMM: f32, KC=512 uniform K-blocks; per element a fresh ascending-k
//         fmaf chain per block; combine ((((0+c0)+c1)+c2)+c3) in f32.
//   Scan: f64 state, un = D*u + y (sep mul/add), s = (un>=1), u = un-s,
//         D = 1/(1+exp(-2)) in f64.
// r28 = r27 (split-K x4, 128x128, 8x8 micro) with the 4-way LDS bank
// conflict fixed: each thread's 8 columns are {tx*4..+3} and {64+tx*4..+3}
// (two float4 groups 64 apart) instead of tx*8..+7. B LDS reads/writes now
// land on banks tx*4%32 -> 2-way aliasing (free). Same fix applied to the
// B staging writes and the ws partial stores.
// Per-element chain arithmetic bit-identical to r15-r27.
// -------------------------------------------------------------------------

// ---- split-K GEMM: one KC=512 chain per block, 8x8 split-col micro ------
__global__ __launch_bounds__(256, 1) void Approx_OTPE_67181878444197_kernel(
        const float* __restrict__ x,
        const float* __restrict__ W,
        float* __restrict__ ws) {
    constexpr int BK = 32, BM = 128, BN = 128;

    __shared__ float As[BK * BM];           // k-major [k][m]  16 KB
    __shared__ float Bs[BK * BN];           // [k][n]          16 KB

    const int o0  = blockIdx.x * BN;
    const int m0  = blockIdx.y * BM;
    const int z   = blockIdx.z;             // KC block 0..3
    const int kz  = z * 512;
    const int tid = threadIdx.x;            // 0..255
    const int ty  = tid >> 4;               // 0..15 -> 8-row group
    const int tx  = tid & 15;               // 0..15 -> split col group

    // A staging: m_local = tid>>1 (0..127), k-half = (tid&1)*16
    const int am = tid >> 1;
    const int ak = (tid & 1) * 16;
    const size_t aBase = (size_t)(m0 + am) * IN_SZ + kz + ak;

    // B staging: rows br, br+16; cols bc4 and 64+bc4 (float4 each)
    const int br  = tid >> 4;               // 0..15
    const int bc4 = (tid & 15) * 4;         // 0..60

    float acc[8][8] = {};   // single KC=512 ascending-k chain (FROZEN)

    #pragma unroll 1
    for (int it = 0; it < 512 / BK; ++it) {
        const int k0 = it * BK;
        const float4 a0 = *reinterpret_cast<const float4*>(&x[aBase + k0]);
        const float4 a1 = *reinterpret_cast<const float4*>(&x[aBase + k0 + 4]);
        const float4 a2 = *reinterpret_cast<const float4*>(&x[aBase + k0 + 8]);
        const float4 a3 = *reinterpret_cast<const float4*>(&x[aBase + k0 + 12]);
        const float4 v0 = *reinterpret_cast<const float4*>(
            &W[(size_t)(kz + k0 + br) * OUT_SZ + o0 + bc4]);
        const float4 v1 = *reinterpret_cast<const float4*>(
            &W[(size_t)(kz + k0 + br) * OUT_SZ + o0 + 64 + bc4]);
        const float4 v2 = *reinterpret_cast<const float4*>(
            &W[(size_t)(kz + k0 + 16 + br) * OUT_SZ + o0 + bc4]);
        const float4 v3 = *reinterpret_cast<const float4*>(
            &W[(size_t)(kz + k0 + 16 + br) * OUT_SZ + o0 + 64 + bc4]);

        __syncthreads();
        As[(ak +  0) * BM + am] = a0.x;
        As[(ak +  1) * BM + am] = a0.y;
        As[(ak +  2) * BM + am] = a0.z;
        As[(ak +  3) * BM + am] = a0.w;
        As[(ak +  4) * BM + am] = a1.x;
        As[(ak +  5) * BM + am] = a1.y;
        As[(ak +  6) * BM + am] = a1.z;
        As[(ak +  7) * BM + am] = a1.w;
        As[(ak +  8) * BM + am] = a2.x;
        As[(ak +  9) * BM + am] = a2.y;
        As[(ak + 10) * BM + am] = a2.z;
        As[(ak + 11) * BM + am] = a2.w;
        As[(ak + 12) * BM + am] = a3.x;
        As[(ak + 13) * BM + am] = a3.y;
        As[(ak + 14) * BM + am] = a3.z;
        As[(ak + 15) * BM + am] = a3.w;
        *reinterpret_cast<float4*>(&Bs[br * BN + bc4])             = v0;
        *reinterpret_cast<float4*>(&Bs[br * BN + 64 + bc4])        = v1;
        *reinterpret_cast<float4*>(&Bs[(br + 16) * BN + bc4])      = v2;
        *reinterpret_cast<float4*>(&Bs[(br + 16) * BN + 64 + bc4]) = v3;
        __syncthreads();

        // ascending k; each acc[i][j] is one strict fmaf chain (FROZEN)
        #pragma unroll
        for (int k = 0; k < BK; ++k) {
            const float4 x0 = *reinterpret_cast<const float4*>(&As[k * BM + ty * 8]);
            const float4 x1 = *reinterpret_cast<const float4*>(&As[k * BM + ty * 8 + 4]);
            const float4 w0 = *reinterpret_cast<const float4*>(&Bs[k * BN + tx * 4]);
            const float4 w1 = *reinterpret_cast<const float4*>(&Bs[k * BN + 64 + tx * 4]);
            const float a[8] = {x0.x, x0.y, x0.z, x0.w, x1.x, x1.y, x1.z, x1.w};
            const float w[8] = {w0.x, w0.y, w0.z, w0.w, w1.x, w1.y, w1.z, w1.w};
            #pragma unroll
            for (int i = 0; i < 8; ++i)
                #pragma unroll
                for (int j = 0; j < 8; ++j)
                    acc[i][j] = __builtin_fmaf(a[i], w[j], acc[i][j]);
        }
    }

    // write partials: cols tx*4 (j=0..3) and 64+tx*4 (j=4..7)
    float* const wz = ws + (size_t)z * M_ROWS * OUT_SZ;
    #pragma unroll
    for (int i = 0; i < 8; ++i) {
        float4 v;
        v.x = acc[i][0]; v.y = acc[i][1]; v.z = acc[i][2]; v.w = acc[i][3];
        float4 v2;
        v2.x = acc[i][4]; v2.y = acc[i][5]; v2.z = acc[i][6]; v2.w = acc[i][7];
        float* const row = &wz[(size_t)(m0 + ty * 8 + i) * OUT_SZ + o0];
        *reinterpret_cast<float4*>(row + tx * 4)      = v;
        *reinterpret_cast<float4*>(row + 64 + tx * 4) = v2;
    }
}

// ---- combine (frozen order) + frozen f64 scan ---------------------------
__global__ __launch_bounds__(256, 1) void snn_combine_scan(
        const float* __restrict__ ws, float* __restrict__ out) {
    const int gid = blockIdx.x * 256 + threadIdx.x;   // 0..B*OUT-1
    const int b   = gid >> 11;                        // /2048
    const int o   = gid & 2047;
    const size_t plane = (size_t)BATCH * OUT_SZ;
    constexpr size_t ZS = (size_t)M_ROWS * OUT_SZ;

    const double D = 1.0 / (1.0 + exp(-2.0));
    double u = 0.0;
    #pragma unroll 1
    for (int t = 0; t < T_STEPS; ++t) {
        const size_t r = (size_t)(t * BATCH + b) * OUT_SZ + o;
        const float p0 = ws[r];
        const float p1 = ws[r + ZS];
        const float p2 = ws[r + 2 * ZS];
        const float p3 = ws[r + 3 * ZS];
        // FROZEN combine: ((((0+c0)+c1)+c2)+c3)
        float y = __fadd_rn(0.0f, p0);
        y = __fadd_rn(y, p1);
        y = __fadd_rn(y, p2);
        y = __fadd_rn(y, p3);
        // FROZEN f64 scan step
        const double un = __dadd_rn(__dmul_rn(D, u), (double)y);
        const double s  = (un >= 1.0) ? 1.0 : 0.0;
        u = __dsub_rn(un, s);
        out[(size_t)t * plane + gid] = (float)s;
    }
}

// ---- fallback: r25 fused kernel (absmax 0.0, 464 us) --------------------
__global__ __launch_bounds__(256, 1) void snn_fused_r25(
        const float* __restrict__ x,
        const float* __restrict__ W,
        float* __restrict__ out) {
    constexpr int BK = 32, BM = 128, BN = 64;
    constexpr int YSTR = BN + 1;
    constexpr int YSZ  = BM * YSTR;

    __shared__ float smem[YSZ];
    float* const As = smem;
    float* const Bs = smem + BK * BM;

    const int o0  = blockIdx.x * BN;
    const int b0  = blockIdx.y * 4;
    const int tid = threadIdx.x;
    const int ty  = tid >> 4;
    const int tx  = tid & 15;

    const int am = tid >> 1;
    const int ak = (tid & 1) * 16;
    const int at = am >> 2;
    const int ab = am & 3;
    const size_t aBase = ((size_t)at * BATCH + (size_t)(b0 + ab)) * IN_SZ + ak;

    const int br = tid >> 4;
    const int bc = (tid & 15) * 4;

    float acc[8][4] = {};
    float su[8][4]  = {};

    #pragma unroll 1
    for (int it = 0; it < IN_SZ / BK; ++it) {
        const int k0 = it * BK;
        const float4 a0 = *reinterpret_cast<const float4*>(&x[aBase + k0]);
        const float4 a1 = *reinterpret_cast<const float4*>(&x[aBase + k0 + 4]);
        const float4 a2 = *reinterpret_cast<const float4*>(&x[aBase + k0 + 8]);
        const float4 a3 = *reinterpret_cast<const float4*>(&x[aBase + k0 + 12]);
        const float4 v0 = *reinterpret_cast<const float4*>(
            &W[(size_t)(k0 + br) * OUT_SZ + o0 + bc]);
        const float4 v1 = *reinterpret_cast<const float4*>(
            &W[(size_t)(k0 + 16 + br) * OUT_SZ + o0 + bc]);

        if (it == 16 || it == 32 || it == 48) {
            #pragma unroll
            for (int i = 0; i < 8; ++i)
                #pragma unroll
                for (int j = 0; j < 4; ++j) {
                    su[i][j]  = __fadd_rn(su[i][j], acc[i][j]);
                    acc[i][j] = 0.0f;
                }
        }

        __syncthreads();
        As[(ak +  0) * BM + am] = a0.x;
        As[(ak +  1) * BM + am] = a0.y;
        As[(ak +  2) * BM + am] = a0.z;
        As[(ak +  3) * BM + am] = a0.w;
        As[(ak +  4) * BM + am] = a1.x;
        As[(ak +  5) * BM + am] = a1.y;
        As[(ak +  6) * BM + am] = a1.z;
        As[(ak +  7) * BM + am] = a1.w;
        As[(ak +  8) * BM + am] = a2.x;
        As[(ak +  9) * BM + am] = a2.y;
        As[(ak + 10) * BM + am] = a2.z;
        As[(ak + 11) * BM + am] = a2.w;
        As[(ak + 12) * BM + am] = a3.x;
        As[(ak + 13) * BM + am] = a3.y;
        As[(ak + 14) * BM + am] = a3.z;
        As[(ak + 15) * BM + am] = a3.w;
        *reinterpret_cast<float4*>(&Bs[br * BN + bc])        = v0;
        *reinterpret_cast<float4*>(&Bs[(br + 16) * BN + bc]) = v1;
        __syncthreads();

        #pragma unroll
        for (int k = 0; k < BK; ++k) {
            const float4 x0 = *reinterpret_cast<const float4*>(&As[k * BM + ty * 8]);
            const float4 x1 = *reinterpret_cast<const float4*>(&As[k * BM + ty * 8 + 4]);
            const float4 wf = *reinterpret_cast<const float4*>(&Bs[k * BN + tx * 4]);
            const float a[8] = {x0.x, x0.y, x0.z, x0.w, x1.x, x1.y, x1.z, x1.w};
            const float w[4] = {wf.x, wf.y, wf.z, wf.w};
            #pragma unroll
            for (int i = 0; i < 8; ++i)
                #pragma unroll
                for (int j = 0; j < 4; ++j)
                    acc[i][j] = __builtin_fmaf(a[i], w[j], acc[i][j]);
        }
    }

    __syncthreads();
    #pragma unroll
    for (int i = 0; i < 8; ++i)
        #pragma unroll
        for (int j = 0; j < 4; ++j)
            smem[(ty * 8 + i) * YSTR + tx * 4 + j] = __fadd_rn(su[i][j], acc[i][j]);
    __syncthreads();

    {
        const int bl = tid >> 6;
        const int o  = tid & 63;
        const size_t plane  = (size_t)BATCH * OUT_SZ;
        const size_t outIdx = (size_t)(b0 + bl) * OUT_SZ + o0 + o;

        const double D = 1.0 / (1.0 + exp(-2.0));
        double u = 0.0;
        #pragma unroll
        for (int t = 0; t < T_STEPS; ++t) {
            const double y  = (double)smem[(t * 4 + bl) * YSTR + o];
            const double un = __dadd_rn(__dmul_rn(D, u), y);
            const double s  = (un >= 1.0) ? 1.0 : 0.0;
            u = __dsub_rn(un, s);
            out[(size_t)t * plane + outIdx] = (float)s;
        }
    }
}

// -------------------------------------------------------------------------
extern "C" void kernel_launch(void* const* d_in, const int* in_sizes, int n_in,
                              void* d_out, int out_size, void* d_ws, size_t ws_size,
                              hipStream_t stream) {
    const float* x = (const float*)d_in[0];   // [T, B, IN] f32
    const float* W = (const float*)d_in[1];   // [IN, OUT] f32
    float* out     = (float*)d_out;           // [T, B, OUT] f32 spikes

    const size_t wsNeeded = (size_t)4 * M_ROWS * OUT_SZ * sizeof(float);
    if (ws_size >= wsNeeded) {
        dim3 g1(OUT_SZ / 128, M_ROWS / 128, 4);   // 16 x 32 x 4 = 2048 blocks
        Approx_OTPE_67181878444197_kernel<<<g1, 256, 0, stream>>>(
            x, W, (float*)d_ws);
        snn_combine_scan<<<(BATCH * OUT_SZ) / 256, 256, 0, stream>>>(
            (const float*)d_ws, out);
    } else {
        dim3 grid(OUT_SZ / 64, BATCH / 4);        // r25 fallback
        snn_fused_r25<<<grid, 256, 0, stream>>>(x, W, out);
    }
}